// Round 1
// baseline (1118.731 us; speedup 1.0000x reference)
//
#include <hip/hip_runtime.h>
#include <math.h>

// ---------------------------------------------------------------------------
// SpatialAlignCrossAttentionCosFormer — fp32 baseline (correctness-first)
// Fixed shapes (idx==10 path): bs=16, c=256, h=w=40, S=1600, T=25600, heads=8, hd=32
// ws layout (float offsets), total 40,001,536 floats = 160,006,144 bytes:
//   pos   [0,        409600)
//   A     [409600,   6963200)   X3 -> attn -> tmp2/out2
//   B     [6963200,  13516800)  X4 -> out1
//   C     [13516800, 20070400)  Q  -> a3p (transposed out2)
//   D     [20070400, 26624000)  K
//   E     [26624000, 33177600)  V  -> tmp1 (pre-LN1)
//   KV    [33177600, 33439744)
//   Ksum  [33439744, 33447936)
//   R     [33447936, 40001536)  residual (a3d, no pos)
//   ffh   [13516800, 39731200)  overlaps C/D/E/KV/Ksum/R (all dead by then)
// ---------------------------------------------------------------------------

__device__ __forceinline__ void fma4(float4& acc, float a, const float4& w) {
  acc.x = fmaf(a, w.x, acc.x);
  acc.y = fmaf(a, w.y, acc.y);
  acc.z = fmaf(a, w.z, acc.z);
  acc.w = fmaf(a, w.w, acc.w);
}

// pos[s][c], s=y*40+x: [sin(y*om), cos(y*om), sin(x*om), cos(x*om)] (64 each)
__global__ void pos_kernel(float* __restrict__ pos) {
  int s = blockIdx.x, c = threadIdx.x;
  int y = s / 40, x = s - y * 40;
  int quad = c >> 6, i = c & 63;
  float omega = expf(-(float)i * (9.2103403719761836f / 64.0f)); // 10000^(-i/64)
  float coord = (quad < 2) ? (float)y : (float)x;
  float a = coord * omega;
  pos[s * 256 + c] = (quad & 1) ? cosf(a) : sinf(a);
}

// a3 (b,c,80,80) -> X3[t][c] = avgpool2 + pos, R[t][c] = avgpool2 ; t = b*1600+y*40+x
__global__ __launch_bounds__(256) void avgpool_kernel(
    const float* __restrict__ a3, const float* __restrict__ pos,
    float* __restrict__ X3, float* __restrict__ R) {
  __shared__ float buf[40 * 257];
  int y = blockIdx.x, b = blockIdx.y;
  int tid = threadIdx.x;
  int wave = tid >> 6, lane = tid & 63;
  if (lane < 40) {
    int x = lane;
    for (int c = wave; c < 256; c += 4) {
      const float* p = a3 + (((size_t)(b * 256 + c) * 80 + 2 * y) * 80 + 2 * x);
      float2 r0 = *(const float2*)p;
      float2 r1 = *(const float2*)(p + 80);
      buf[x * 257 + c] = 0.25f * ((r0.x + r0.y) + (r1.x + r1.y));
    }
  }
  __syncthreads();
  size_t t0 = (size_t)b * 1600 + y * 40;
  int sbase = y * 40;
  for (int it = 0; it < 40; ++it) {
    float v = buf[it * 257 + tid];
    X3[(t0 + it) * 256 + tid] = v + pos[(size_t)(sbase + it) * 256 + tid];
    R[(t0 + it) * 256 + tid] = v;
  }
}

// Tiled fp32 GEMM: Cout[t][o] = epi( sum_k A[t][k] * Wm[o][k] + bias[o] )
// CONV: A[t][k] = a4[b][k][s] (t=b*1600+s), K=512
// MODE 0: +bias ; MODE 1: conv-BN(+pos) ; MODE 2: +bias then exact GELU
template<int MODE, bool CONV>
__global__ __launch_bounds__(256) void gemm_kernel(
    const float* __restrict__ A, const float* __restrict__ Wm,
    const float* __restrict__ bias, float* __restrict__ Cout,
    int K, int N,
    const float* __restrict__ pos,
    const float* __restrict__ bn_g, const float* __restrict__ bn_b) {
  __shared__ float Alds[32][128];
  __shared__ float Wlds[32][128];
  int tid = threadIdx.x;
  int tx = tid & 15, ty = tid >> 4;
  int t0 = blockIdx.x * 128, o0 = blockIdx.y * 128;
  float4 acc[2][4][2];
#pragma unroll
  for (int a = 0; a < 2; ++a)
#pragma unroll
    for (int i = 0; i < 4; ++i)
#pragma unroll
      for (int o = 0; o < 2; ++o)
        acc[a][i][o] = make_float4(0.f, 0.f, 0.f, 0.f);

  for (int k0 = 0; k0 < K; k0 += 32) {
    __syncthreads();
    if (CONV) {
#pragma unroll
      for (int p = 0; p < 4; ++p) {
        int idx = p * 256 + tid;
        int kk = idx >> 5, tq = idx & 31;
        int t = t0 + tq * 4;                     // 4-aligned; batch bound is 4-aligned too
        int bb = t / 1600;
        int ss = t - bb * 1600;
        float4 v = *(const float4*)(A + (size_t)bb * K * 1600 + (size_t)(k0 + kk) * 1600 + ss);
        *(float4*)&Alds[kk][tq * 4] = v;
      }
    } else {
#pragma unroll
      for (int p = 0; p < 4; ++p) {
        int idx = p * 256 + tid;
        int r = idx >> 3, c4 = (idx & 7) * 4;
        float4 v = *(const float4*)(A + (size_t)(t0 + r) * K + (k0 + c4));
        Alds[c4 + 0][r] = v.x;
        Alds[c4 + 1][r] = v.y;
        Alds[c4 + 2][r] = v.z;
        Alds[c4 + 3][r] = v.w;
      }
    }
#pragma unroll
    for (int p = 0; p < 4; ++p) {
      int idx = p * 256 + tid;
      int r = idx >> 3, c4 = (idx & 7) * 4;
      float4 v = *(const float4*)(Wm + (size_t)(o0 + r) * K + (k0 + c4));
      Wlds[c4 + 0][r] = v.x;
      Wlds[c4 + 1][r] = v.y;
      Wlds[c4 + 2][r] = v.z;
      Wlds[c4 + 3][r] = v.w;
    }
    __syncthreads();
#pragma unroll
    for (int kk = 0; kk < 32; ++kk) {
      float4 a0 = *(const float4*)&Alds[kk][ty * 4];
      float4 a1 = *(const float4*)&Alds[kk][64 + ty * 4];
      float4 w0 = *(const float4*)&Wlds[kk][tx * 4];
      float4 w1 = *(const float4*)&Wlds[kk][64 + tx * 4];
      fma4(acc[0][0][0], a0.x, w0); fma4(acc[0][0][1], a0.x, w1);
      fma4(acc[0][1][0], a0.y, w0); fma4(acc[0][1][1], a0.y, w1);
      fma4(acc[0][2][0], a0.z, w0); fma4(acc[0][2][1], a0.z, w1);
      fma4(acc[0][3][0], a0.w, w0); fma4(acc[0][3][1], a0.w, w1);
      fma4(acc[1][0][0], a1.x, w0); fma4(acc[1][0][1], a1.x, w1);
      fma4(acc[1][1][0], a1.y, w0); fma4(acc[1][1][1], a1.y, w1);
      fma4(acc[1][2][0], a1.z, w0); fma4(acc[1][2][1], a1.z, w1);
      fma4(acc[1][3][0], a1.w, w0); fma4(acc[1][3][1], a1.w, w1);
    }
  }
#pragma unroll
  for (int th = 0; th < 2; ++th)
#pragma unroll
    for (int i = 0; i < 4; ++i) {
      int t = t0 + th * 64 + ty * 4 + i;
#pragma unroll
      for (int oh = 0; oh < 2; ++oh) {
        int o = o0 + oh * 64 + tx * 4;
        float4 r = acc[th][i][oh];
        float4 bb = *(const float4*)(bias + o);
        r.x += bb.x; r.y += bb.y; r.z += bb.z; r.w += bb.w;
        if (MODE == 1) {
          const float is = 0.99999500003749968f;  // 1/sqrt(1+1e-5)
          float4 g = *(const float4*)(bn_g + o);
          float4 b2 = *(const float4*)(bn_b + o);
          int ss = t % 1600;
          float4 pz = *(const float4*)(pos + (size_t)ss * 256 + o);
          r.x = r.x * (is * g.x) + b2.x + pz.x;
          r.y = r.y * (is * g.y) + b2.y + pz.y;
          r.z = r.z * (is * g.z) + b2.z + pz.z;
          r.w = r.w * (is * g.w) + b2.w + pz.w;
        }
        if (MODE == 2) {
          r.x = 0.5f * r.x * (1.f + erff(r.x * 0.7071067811865475f));
          r.y = 0.5f * r.y * (1.f + erff(r.y * 0.7071067811865475f));
          r.z = 0.5f * r.z * (1.f + erff(r.z * 0.7071067811865475f));
          r.w = 0.5f * r.w * (1.f + erff(r.w * 0.7071067811865475f));
        }
        *(float4*)(Cout + (size_t)t * N + o) = r;
      }
    }
}

// Row LayerNorm over 256, one wave per row. MODE 0: ReLU(LN(x)); MODE 1: res + LN(x)
template<int MODE>
__global__ __launch_bounds__(256) void ln_kernel(
    const float* __restrict__ X, const float* __restrict__ g, const float* __restrict__ b,
    const float* __restrict__ res, float* __restrict__ out) {
  int t = blockIdx.x * 4 + (threadIdx.x >> 6);
  int lane = threadIdx.x & 63;
  size_t rowo = (size_t)t * 256 + lane * 4;
  float4 x = *(const float4*)(X + rowo);
  float s = (x.x + x.y) + (x.z + x.w);
#pragma unroll
  for (int off = 32; off > 0; off >>= 1) s += __shfl_xor(s, off);
  float m = s * (1.0f / 256.0f);
  float d0 = x.x - m, d1 = x.y - m, d2 = x.z - m, d3 = x.w - m;
  float ssum = (d0 * d0 + d1 * d1) + (d2 * d2 + d3 * d3);
#pragma unroll
  for (int off = 32; off > 0; off >>= 1) ssum += __shfl_xor(ssum, off);
  float inv = 1.0f / sqrtf(ssum * (1.0f / 256.0f) + 1e-5f);
  float4 gv = *(const float4*)(g + lane * 4);
  float4 bv = *(const float4*)(b + lane * 4);
  float4 y;
  y.x = d0 * inv * gv.x + bv.x;
  y.y = d1 * inv * gv.y + bv.y;
  y.z = d2 * inv * gv.z + bv.z;
  y.w = d3 * inv * gv.w + bv.w;
  if (MODE == 0) {
    y.x = fmaxf(y.x, 0.f); y.y = fmaxf(y.y, 0.f);
    y.z = fmaxf(y.z, 0.f); y.w = fmaxf(y.w, 0.f);
  } else {
    float4 rv = *(const float4*)(res + rowo);
    y.x += rv.x; y.y += rv.y; y.z += rv.z; y.w += rv.w;
  }
  *(float4*)(out + rowo) = y;
}

// Per (b,h): KV[d][e] = sum_s K_[s][d] V[s][e]; Ksum[d] = sum_s K_[s][d]
// K_[s][d] = K[s][d]*sin(wi_s) (d<32) | K[s][d-32]*cos(wi_s) (d>=32)
__global__ __launch_bounds__(256) void kv_kernel(
    const float* __restrict__ Kb, const float* __restrict__ Vb,
    float* __restrict__ KV, float* __restrict__ Ksum) {
  __shared__ float Kc[64][32];
  __shared__ float Vc[64][32];
  __shared__ float sv[64], cv[64];
  __shared__ float red[4][64];
  int bh = blockIdx.x;
  int b = bh >> 3, h = bh & 7;
  int tid = threadIdx.x;
  int e = tid & 31, dg = tid >> 5;   // dg 0..7
  int d4 = dg * 4;
  int dks = tid & 63, part = tid >> 6;
  float accs[4] = {0.f, 0.f, 0.f, 0.f};
  float accc[4] = {0.f, 0.f, 0.f, 0.f};
  float ks = 0.f;
  size_t base = ((size_t)b * 1600) * 256 + h * 32;
  for (int s0 = 0; s0 < 1600; s0 += 64) {
    __syncthreads();
#pragma unroll
    for (int p = 0; p < 8; ++p) {
      int si = dg + p * 8;
      Kc[si][e] = Kb[base + (size_t)(s0 + si) * 256 + e];
      Vc[si][e] = Vb[base + (size_t)(s0 + si) * 256 + e];
    }
    if (tid < 64) {
      float wv = 1.5707963267948966f * (float)(s0 + tid + 1) * (1.0f / 1600.0f);
      sv[tid] = sinf(wv);
      cv[tid] = cosf(wv);
    }
    __syncthreads();
#pragma unroll 8
    for (int si = 0; si < 64; ++si) {
      float vv = Vc[si][e];
      float sn = sv[si], cs = cv[si];
      float4 k4 = *(const float4*)&Kc[si][d4];
      float p0 = k4.x * vv, p1 = k4.y * vv, p2 = k4.z * vv, p3 = k4.w * vv;
      accs[0] = fmaf(p0, sn, accs[0]); accc[0] = fmaf(p0, cs, accc[0]);
      accs[1] = fmaf(p1, sn, accs[1]); accc[1] = fmaf(p1, cs, accc[1]);
      accs[2] = fmaf(p2, sn, accs[2]); accc[2] = fmaf(p2, cs, accc[2]);
      accs[3] = fmaf(p3, sn, accs[3]); accc[3] = fmaf(p3, cs, accc[3]);
    }
#pragma unroll 4
    for (int q = 0; q < 16; ++q) {
      int si = part * 16 + q;
      float kvv = (dks < 32) ? Kc[si][dks] * sv[si] : Kc[si][dks - 32] * cv[si];
      ks += kvv;
    }
  }
  red[part][dks] = ks;
  __syncthreads();
  if (tid < 64)
    Ksum[(size_t)bh * 64 + tid] = (red[0][tid] + red[1][tid]) + (red[2][tid] + red[3][tid]);
#pragma unroll
  for (int i = 0; i < 4; ++i) {
    KV[(size_t)bh * 2048 + (d4 + i) * 32 + e] = accs[i];
    KV[(size_t)bh * 2048 + (32 + d4 + i) * 32 + e] = accc[i];
  }
}

// attn[t][h*32+e] = (sum_d Q_[t,d] KV[bh][d][e]) / clip(sum_d Q_[t,d] Ksum[bh][d], 1e-4, 10)
__global__ __launch_bounds__(256) void attn_kernel(
    const float* __restrict__ Qb, const float* __restrict__ KV,
    const float* __restrict__ Ksum, float* __restrict__ attn) {
  int grp = threadIdx.x >> 5;
  int e = threadIdx.x & 31;
  int t = blockIdx.x * 8 + grp;
  int b = t / 1600, s = t - b * 1600;
  float wv = 1.5707963267948966f * (float)(s + 1) * (1.0f / 1600.0f);
  float sq = sinf(wv), cq = cosf(wv);
  const float* qrow = Qb + (size_t)t * 256;
  for (int h = 0; h < 8; ++h) {
    int bh = b * 8 + h;
    const float* kv = KV + (size_t)bh * 2048;
    const float* ksm = Ksum + (size_t)bh * 64;
    float acc = 0.f, zden = 0.f;
#pragma unroll 8
    for (int d = 0; d < 32; ++d) {
      float qv = qrow[h * 32 + d];
      float qs = qv * sq, qc = qv * cq;
      acc = fmaf(qs, kv[d * 32 + e], acc);
      acc = fmaf(qc, kv[(32 + d) * 32 + e], acc);
      zden = fmaf(qs, ksm[d], zden);
      zden = fmaf(qc, ksm[32 + d], zden);
    }
    float zc = fminf(fmaxf(zden, 1e-4f), 10.0f);
    attn[(size_t)t * 256 + h * 32 + e] = acc * (1.0f / zc);
  }
}

// out2 [t][256] -> a3p [b][c][40][40]
__global__ __launch_bounds__(256) void transpose_kernel(
    const float* __restrict__ X, float* __restrict__ Y) {
  __shared__ float buf[40 * 257];
  int y = blockIdx.x, b = blockIdx.y;
  int tid = threadIdx.x;
  size_t t0 = (size_t)b * 1600 + y * 40;
  for (int it = 0; it < 40; ++it)
    buf[it * 257 + tid] = X[(t0 + it) * 256 + tid];
  __syncthreads();
  for (int it = 0; it < 40; ++it) {
    int idx = it * 256 + tid;
    int c = idx / 40, x = idx - c * 40;
    Y[((size_t)(b * 256 + c) * 1600) + y * 40 + x] = buf[x * 257 + c];
  }
}

// half-pixel bilinear 40->80 with edge clamp (== JAX renormalized weights for scale 2)
__device__ __forceinline__ float bilin40(const float* sm, int Y, int X) {
  float fy = Y * 0.5f - 0.25f;
  int iy = (int)floorf(fy);
  float dy = fy - (float)iy;
  int y0 = iy < 0 ? 0 : iy;
  int y1 = (iy + 1) > 39 ? 39 : (iy + 1);
  float fx = X * 0.5f - 0.25f;
  int ix = (int)floorf(fx);
  float dx = fx - (float)ix;
  int x0 = ix < 0 ? 0 : ix;
  int x1 = (ix + 1) > 39 ? 39 : (ix + 1);
  float v00 = sm[y0 * 40 + x0], v01 = sm[y0 * 40 + x1];
  float v10 = sm[y1 * 40 + x0], v11 = sm[y1 * 40 + x1];
  return (1.f - dy) * ((1.f - dx) * v00 + dx * v01) +
         dy * ((1.f - dx) * v10 + dx * v11);
}

__global__ __launch_bounds__(256) void upsample_mul_kernel(
    const float* __restrict__ src, const float* __restrict__ a3, float* __restrict__ out) {
  __shared__ float sm[1600];
  int c = blockIdx.x, b = blockIdx.y;
  size_t sbase = ((size_t)b * 256 + c) * 1600;
  for (int i = threadIdx.x; i < 1600; i += 256) sm[i] = src[sbase + i];
  __syncthreads();
  size_t obase = ((size_t)b * 256 + c) * 6400;
  for (int it = 0; it < 25; ++it) {
    int idx = it * 256 + threadIdx.x;
    int Y = idx / 80, X = idx - Y * 80;
    out[obase + idx] = bilin40(sm, Y, X) * a3[obase + idx];
  }
}

__global__ __launch_bounds__(256) void upsample_kernel(
    const float* __restrict__ src, float* __restrict__ out) {
  __shared__ float sm[1600];
  int c = blockIdx.x, b = blockIdx.y;
  size_t sbase = ((size_t)b * 512 + c) * 1600;
  for (int i = threadIdx.x; i < 1600; i += 256) sm[i] = src[sbase + i];
  __syncthreads();
  size_t obase = ((size_t)b * 512 + c) * 6400;
  for (int it = 0; it < 25; ++it) {
    int idx = it * 256 + threadIdx.x;
    int Y = idx / 80, X = idx - Y * 80;
    out[obase + idx] = bilin40(sm, Y, X);
  }
}

extern "C" void kernel_launch(void* const* d_in, const int* in_sizes, int n_in,
                              void* d_out, int out_size, void* d_ws, size_t ws_size,
                              hipStream_t stream) {
  const float* a3     = (const float*)d_in[0];
  const float* a4     = (const float*)d_in[1];
  const float* conv_w = (const float*)d_in[2];
  const float* conv_b = (const float*)d_in[3];
  const float* bn_g   = (const float*)d_in[4];
  const float* bn_b   = (const float*)d_in[5];
  const float* q_w    = (const float*)d_in[6];
  const float* q_b    = (const float*)d_in[7];
  const float* q_ln_g = (const float*)d_in[8];
  const float* q_ln_b = (const float*)d_in[9];
  const float* k_w    = (const float*)d_in[10];
  const float* k_b    = (const float*)d_in[11];
  const float* k_ln_g = (const float*)d_in[12];
  const float* k_ln_b = (const float*)d_in[13];
  const float* v_w    = (const float*)d_in[14];
  const float* v_b    = (const float*)d_in[15];
  const float* out_w  = (const float*)d_in[16];
  const float* out_b  = (const float*)d_in[17];
  const float* lin1_w = (const float*)d_in[18];
  const float* lin1_b = (const float*)d_in[19];
  const float* lin2_w = (const float*)d_in[20];
  const float* lin2_b = (const float*)d_in[21];
  const float* n1_g   = (const float*)d_in[22];
  const float* n1_b   = (const float*)d_in[23];
  const float* n2_g   = (const float*)d_in[24];
  const float* n2_b   = (const float*)d_in[25];
  (void)in_sizes; (void)n_in; (void)out_size; (void)ws_size;

  float* ws  = (float*)d_ws;
  float* pos = ws + 0;
  float* X3  = ws + 409600;    // slot A: X3 -> attn -> tmp2/out2
  float* X4  = ws + 6963200;   // slot B: X4 -> out1
  float* Qb  = ws + 13516800;  // slot C: Q -> a3p
  float* Kb  = ws + 20070400;  // slot D
  float* Vb  = ws + 26624000;  // slot E: V -> tmp1
  float* KV  = ws + 33177600;
  float* Ks  = ws + 33439744;
  float* Rb  = ws + 33447936;
  float* ffh = ws + 13516800;  // overlaps C..R (dead by lin1)
  float* out0 = (float*)d_out;
  float* out1 = out0 + (size_t)16 * 256 * 80 * 80;

  pos_kernel<<<1600, 256, 0, stream>>>(pos);
  avgpool_kernel<<<dim3(40, 16), 256, 0, stream>>>(a3, pos, X3, Rb);
  // conv 1x1 + BN + pos -> X4
  gemm_kernel<1, true><<<dim3(200, 2), 256, 0, stream>>>(a4, conv_w, conv_b, X4, 512, 256, pos, bn_g, bn_b);
  // Q = relu(LN(X3 @ q_w^T + q_b))
  gemm_kernel<0, false><<<dim3(200, 2), 256, 0, stream>>>(X3, q_w, q_b, Qb, 256, 256, nullptr, nullptr, nullptr);
  ln_kernel<0><<<6400, 256, 0, stream>>>(Qb, q_ln_g, q_ln_b, nullptr, Qb);
  // K = relu(LN(X4 @ k_w^T + k_b))
  gemm_kernel<0, false><<<dim3(200, 2), 256, 0, stream>>>(X4, k_w, k_b, Kb, 256, 256, nullptr, nullptr, nullptr);
  ln_kernel<0><<<6400, 256, 0, stream>>>(Kb, k_ln_g, k_ln_b, nullptr, Kb);
  // V = X4 @ v_w^T + v_b
  gemm_kernel<0, false><<<dim3(200, 2), 256, 0, stream>>>(X4, v_w, v_b, Vb, 256, 256, nullptr, nullptr, nullptr);
  // linear attention
  kv_kernel<<<128, 256, 0, stream>>>(Kb, Vb, KV, Ks);
  attn_kernel<<<3200, 256, 0, stream>>>(Qb, KV, Ks, X3 /*attn*/);
  // out-proj -> tmp1 (slot E), then out1 = R + LN1(tmp1) (slot B)
  gemm_kernel<0, false><<<dim3(200, 2), 256, 0, stream>>>(X3, out_w, out_b, Vb, 256, 256, nullptr, nullptr, nullptr);
  ln_kernel<1><<<6400, 256, 0, stream>>>(Vb, n1_g, n1_b, Rb, X4 /*out1*/);
  // FFN
  gemm_kernel<2, false><<<dim3(200, 8), 256, 0, stream>>>(X4, lin1_w, lin1_b, ffh, 256, 1024, nullptr, nullptr, nullptr);
  gemm_kernel<0, false><<<dim3(200, 2), 256, 0, stream>>>(ffh, lin2_w, lin2_b, X3 /*tmp2*/, 1024, 256, nullptr, nullptr, nullptr);
  ln_kernel<1><<<6400, 256, 0, stream>>>(X3, n2_g, n2_b, X4 /*res=out1*/, X3 /*out2 in-place*/);
  // out2 [t][c] -> a3p [b][c][40][40], then upsample*a3 ; a4 upsample
  transpose_kernel<<<dim3(40, 16), 256, 0, stream>>>(X3, Qb /*a3p*/);
  upsample_mul_kernel<<<dim3(256, 16), 256, 0, stream>>>(Qb, a3, out0);
  upsample_kernel<<<dim3(512, 16), 256, 0, stream>>>(a4, out1);
}

// Round 2
// 677.016 us; speedup vs baseline: 1.6524x; 1.6524x over previous
//
#include <hip/hip_runtime.h>
#include <math.h>

// ---------------------------------------------------------------------------
// SpatialAlignCrossAttentionCosFormer — Round 2: bf16-MFMA GEMMs
// Fixed shapes (idx==10): bs=16, c=256, h=w=40, S=1600, T=25600, heads=8, hd=32
// ws layout (float offsets):
//   pos   [0,        409600)
//   A     [409600,   6963200)   X3 -> attn -> tmp2/out2
//   B     [6963200,  13516800)  X4 -> out1
//   C     [13516800, 20070400)  Q  -> a3p           (a4t lives in C+D first)
//   D     [20070400, 26624000)  K
//   E     [26624000, 33177600)  V  -> tmp1 (pre-LN1)
//   KV    [33177600, 33439744)
//   Ksum  [33439744, 33447936)
//   R     [33447936, 40001536)  residual (a3d, no pos)
//   ffh   [13516800, 39731200)  overlaps C/D/E/KV/Ksum/R (dead by lin1)
// ---------------------------------------------------------------------------

typedef __attribute__((ext_vector_type(8))) short bf16x8;
typedef __attribute__((ext_vector_type(4))) float f32x4;
typedef __attribute__((ext_vector_type(4))) unsigned short us4;

__device__ __forceinline__ unsigned short f2bf(float f) {
  unsigned int u = __float_as_uint(f);
  u += 0x7fff + ((u >> 16) & 1);   // RNE
  return (unsigned short)(u >> 16);
}

// pos[s][c], s=y*40+x: [sin(y*om), cos(y*om), sin(x*om), cos(x*om)] (64 each)
__global__ void pos_kernel(float* __restrict__ pos) {
  int s = blockIdx.x, c = threadIdx.x;
  int y = s / 40, x = s - y * 40;
  int quad = c >> 6, i = c & 63;
  float omega = expf(-(float)i * (9.2103403719761836f / 64.0f)); // 10000^(-i/64)
  float coord = (quad < 2) ? (float)y : (float)x;
  float a = coord * omega;
  pos[s * 256 + c] = (quad & 1) ? cosf(a) : sinf(a);
}

// a3 (b,c,80,80) -> X3[t][c] = avgpool2 + pos, R[t][c] = avgpool2 ; t=b*1600+y*40+x
__global__ __launch_bounds__(256) void avgpool_kernel(
    const float* __restrict__ a3, const float* __restrict__ pos,
    float* __restrict__ X3, float* __restrict__ R) {
  __shared__ float buf[40 * 257];
  int y = blockIdx.x, b = blockIdx.y;
  int tid = threadIdx.x;
  int wave = tid >> 6, lane = tid & 63;
  if (lane < 40) {
    int x = lane;
    for (int c = wave; c < 256; c += 4) {
      const float* p = a3 + (((size_t)(b * 256 + c) * 80 + 2 * y) * 80 + 2 * x);
      float2 r0 = *(const float2*)p;
      float2 r1 = *(const float2*)(p + 80);
      buf[x * 257 + c] = 0.25f * ((r0.x + r0.y) + (r1.x + r1.y));
    }
  }
  __syncthreads();
  size_t t0 = (size_t)b * 1600 + y * 40;
  int sbase = y * 40;
  for (int it = 0; it < 40; ++it) {
    float v = buf[it * 257 + tid];
    X3[(t0 + it) * 256 + tid] = v + pos[(size_t)(sbase + it) * 256 + tid];
    R[(t0 + it) * 256 + tid] = v;
  }
}

// a4 [b][k][s] -> a4t [b*1600+s][k]   (16, 512, 1600) -> (25600, 512)
__global__ __launch_bounds__(256) void a4t_kernel(
    const float* __restrict__ a4, float* __restrict__ a4t) {
  __shared__ float buf[64][65];
  int s0 = blockIdx.x * 64, k0 = blockIdx.y * 64, b = blockIdx.z;
  const float* src = a4 + ((size_t)b * 512 + k0) * 1600 + s0;
#pragma unroll
  for (int p = 0; p < 4; ++p) {
    int idx = p * 256 + threadIdx.x;
    int kk = idx >> 4, s4 = (idx & 15) * 4;
    float4 v = *(const float4*)(src + (size_t)kk * 1600 + s4);
    buf[kk][s4 + 0] = v.x; buf[kk][s4 + 1] = v.y;
    buf[kk][s4 + 2] = v.z; buf[kk][s4 + 3] = v.w;
  }
  __syncthreads();
  float* dst = a4t + ((size_t)b * 1600 + s0) * 512 + k0;
#pragma unroll
  for (int p = 0; p < 4; ++p) {
    int idx = p * 256 + threadIdx.x;
    int ss = idx >> 4, kq = (idx & 15) * 4;
    float4 v = make_float4(buf[kq][ss], buf[kq + 1][ss], buf[kq + 2][ss], buf[kq + 3][ss]);
    *(float4*)(dst + (size_t)ss * 512 + kq) = v;
  }
}

// ---------------------------------------------------------------------------
// bf16-MFMA GEMM: Cout[t][o] = epi( sum_k A[t][k]*Wm[o][k] + bias[o] )
// A: [M=25600][K] fp32 row-major, Wm: [N][K] fp32 row-major.
// Tile 128x128, BK=32, 4 waves each 64x64 (4x4 frags of 16x16x32).
// k-map trick: frag k index = (lane>>4)*8 + r for BOTH A and B -> any common
// bijection is correct; only the C/D layout (col=lane&15,row=(lane>>4)*4+i) is assumed.
// MODE 0: +bias ; MODE 1: conv-BN + pos ; MODE 2: +bias then exact GELU
// ---------------------------------------------------------------------------
template<int MODE>
__global__ __launch_bounds__(256) void mgemm_kernel(
    const float* __restrict__ A, const float* __restrict__ Wm,
    const float* __restrict__ bias, float* __restrict__ Cout,
    int K, int N,
    const float* __restrict__ pos,
    const float* __restrict__ bn_g, const float* __restrict__ bn_b) {
  __shared__ short Albs[128][40];   // [m][k], row padded 32->40 (2-way max conflict)
  __shared__ short Wlds[128][40];   // [n][k]
  int tid = threadIdx.x;
  int lane = tid & 63, wave = tid >> 6;
  int m0 = (wave >> 1) * 64, n0 = (wave & 1) * 64;
  int t0 = blockIdx.x * 128, o0 = blockIdx.y * 128;
  f32x4 acc[4][4] = {};

  for (int k0 = 0; k0 < K; k0 += 32) {
    __syncthreads();
#pragma unroll
    for (int p = 0; p < 4; ++p) {
      int idx = p * 256 + tid;
      int rr = idx >> 3, cc = (idx & 7) * 4;
      float4 va = *(const float4*)(A + (size_t)(t0 + rr) * K + (k0 + cc));
      us4 ua; ua[0] = f2bf(va.x); ua[1] = f2bf(va.y); ua[2] = f2bf(va.z); ua[3] = f2bf(va.w);
      *(us4*)&Albs[rr][cc] = ua;
      float4 vw = *(const float4*)(Wm + (size_t)(o0 + rr) * K + (k0 + cc));
      us4 uw; uw[0] = f2bf(vw.x); uw[1] = f2bf(vw.y); uw[2] = f2bf(vw.z); uw[3] = f2bf(vw.w);
      *(us4*)&Wlds[rr][cc] = uw;
    }
    __syncthreads();
    bf16x8 af[4], bfr[4];
#pragma unroll
    for (int ms = 0; ms < 4; ++ms)
      af[ms] = *(bf16x8*)&Albs[m0 + ms * 16 + (lane & 15)][(lane >> 4) * 8];
#pragma unroll
    for (int ns = 0; ns < 4; ++ns)
      bfr[ns] = *(bf16x8*)&Wlds[n0 + ns * 16 + (lane & 15)][(lane >> 4) * 8];
#pragma unroll
    for (int ms = 0; ms < 4; ++ms)
#pragma unroll
      for (int ns = 0; ns < 4; ++ns)
        acc[ms][ns] = __builtin_amdgcn_mfma_f32_16x16x32_bf16(af[ms], bfr[ns], acc[ms][ns], 0, 0, 0);
  }

  int col_l = lane & 15, row_l = (lane >> 4) * 4;
  const float is = 0.99999500003749968f;  // 1/sqrt(1+1e-5)
#pragma unroll
  for (int ns = 0; ns < 4; ++ns) {
    int o = o0 + n0 + ns * 16 + col_l;
    float bv = bias[o];
    float gg = 0.f, b2 = 0.f;
    if (MODE == 1) { gg = is * bn_g[o]; b2 = bn_b[o]; }
#pragma unroll
    for (int ms = 0; ms < 4; ++ms) {
#pragma unroll
      for (int i = 0; i < 4; ++i) {
        int t = t0 + m0 + ms * 16 + row_l + i;
        float rv = acc[ms][ns][i] + bv;
        if (MODE == 1) {
          int ss = t % 1600;
          rv = rv * gg + b2 + pos[(size_t)ss * 256 + o];
        }
        if (MODE == 2)
          rv = 0.5f * rv * (1.f + erff(rv * 0.7071067811865475f));
        Cout[(size_t)t * N + o] = rv;
      }
    }
  }
}

// Row LayerNorm over 256, one wave per row. MODE 0: ReLU(LN(x)); MODE 1: res + LN(x)
template<int MODE>
__global__ __launch_bounds__(256) void ln_kernel(
    const float* __restrict__ X, const float* __restrict__ g, const float* __restrict__ b,
    const float* __restrict__ res, float* __restrict__ out) {
  int t = blockIdx.x * 4 + (threadIdx.x >> 6);
  int lane = threadIdx.x & 63;
  size_t rowo = (size_t)t * 256 + lane * 4;
  float4 x = *(const float4*)(X + rowo);
  float s = (x.x + x.y) + (x.z + x.w);
#pragma unroll
  for (int off = 32; off > 0; off >>= 1) s += __shfl_xor(s, off);
  float m = s * (1.0f / 256.0f);
  float d0 = x.x - m, d1 = x.y - m, d2 = x.z - m, d3 = x.w - m;
  float ssum = (d0 * d0 + d1 * d1) + (d2 * d2 + d3 * d3);
#pragma unroll
  for (int off = 32; off > 0; off >>= 1) ssum += __shfl_xor(ssum, off);
  float inv = 1.0f / sqrtf(ssum * (1.0f / 256.0f) + 1e-5f);
  float4 gv = *(const float4*)(g + lane * 4);
  float4 bv = *(const float4*)(b + lane * 4);
  float4 y;
  y.x = d0 * inv * gv.x + bv.x;
  y.y = d1 * inv * gv.y + bv.y;
  y.z = d2 * inv * gv.z + bv.z;
  y.w = d3 * inv * gv.w + bv.w;
  if (MODE == 0) {
    y.x = fmaxf(y.x, 0.f); y.y = fmaxf(y.y, 0.f);
    y.z = fmaxf(y.z, 0.f); y.w = fmaxf(y.w, 0.f);
  } else {
    float4 rv = *(const float4*)(res + rowo);
    y.x += rv.x; y.y += rv.y; y.z += rv.z; y.w += rv.w;
  }
  *(float4*)(out + rowo) = y;
}

// Per (b,h): KV[d][e] = sum_s K_[s][d] V[s][e]; Ksum[d] = sum_s K_[s][d]
__global__ __launch_bounds__(256) void kv_kernel(
    const float* __restrict__ Kb, const float* __restrict__ Vb,
    float* __restrict__ KV, float* __restrict__ Ksum) {
  __shared__ float Kc[64][32];
  __shared__ float Vc[64][32];
  __shared__ float sv[64], cv[64];
  __shared__ float red[4][64];
  int bh = blockIdx.x;
  int b = bh >> 3, h = bh & 7;
  int tid = threadIdx.x;
  int e = tid & 31, dg = tid >> 5;
  int d4 = dg * 4;
  int dks = tid & 63, part = tid >> 6;
  float accs[4] = {0.f, 0.f, 0.f, 0.f};
  float accc[4] = {0.f, 0.f, 0.f, 0.f};
  float ks = 0.f;
  size_t base = ((size_t)b * 1600) * 256 + h * 32;
  for (int s0 = 0; s0 < 1600; s0 += 64) {
    __syncthreads();
#pragma unroll
    for (int p = 0; p < 8; ++p) {
      int si = dg + p * 8;
      Kc[si][e] = Kb[base + (size_t)(s0 + si) * 256 + e];
      Vc[si][e] = Vb[base + (size_t)(s0 + si) * 256 + e];
    }
    if (tid < 64) {
      float wv = 1.5707963267948966f * (float)(s0 + tid + 1) * (1.0f / 1600.0f);
      sv[tid] = sinf(wv);
      cv[tid] = cosf(wv);
    }
    __syncthreads();
#pragma unroll 8
    for (int si = 0; si < 64; ++si) {
      float vv = Vc[si][e];
      float sn = sv[si], cs = cv[si];
      float4 k4 = *(const float4*)&Kc[si][d4];
      float p0 = k4.x * vv, p1 = k4.y * vv, p2 = k4.z * vv, p3 = k4.w * vv;
      accs[0] = fmaf(p0, sn, accs[0]); accc[0] = fmaf(p0, cs, accc[0]);
      accs[1] = fmaf(p1, sn, accs[1]); accc[1] = fmaf(p1, cs, accc[1]);
      accs[2] = fmaf(p2, sn, accs[2]); accc[2] = fmaf(p2, cs, accc[2]);
      accs[3] = fmaf(p3, sn, accs[3]); accc[3] = fmaf(p3, cs, accc[3]);
    }
#pragma unroll 4
    for (int q = 0; q < 16; ++q) {
      int si = part * 16 + q;
      float kvv = (dks < 32) ? Kc[si][dks] * sv[si] : Kc[si][dks - 32] * cv[si];
      ks += kvv;
    }
  }
  red[part][dks] = ks;
  __syncthreads();
  if (tid < 64)
    Ksum[(size_t)bh * 64 + tid] = (red[0][tid] + red[1][tid]) + (red[2][tid] + red[3][tid]);
#pragma unroll
  for (int i = 0; i < 4; ++i) {
    KV[(size_t)bh * 2048 + (d4 + i) * 32 + e] = accs[i];
    KV[(size_t)bh * 2048 + (32 + d4 + i) * 32 + e] = accc[i];
  }
}

// attn[t][h*32+e] = (sum_d Q_[t,d] KV[bh][d][e]) / clip(sum_d Q_[t,d] Ksum[bh][d])
__global__ __launch_bounds__(256) void attn_kernel(
    const float* __restrict__ Qb, const float* __restrict__ KV,
    const float* __restrict__ Ksum, float* __restrict__ attn) {
  int grp = threadIdx.x >> 5;
  int e = threadIdx.x & 31;
  int t = blockIdx.x * 8 + grp;
  int b = t / 1600, s = t - b * 1600;
  float wv = 1.5707963267948966f * (float)(s + 1) * (1.0f / 1600.0f);
  float sq = sinf(wv), cq = cosf(wv);
  const float* qrow = Qb + (size_t)t * 256;
  for (int h = 0; h < 8; ++h) {
    int bh = b * 8 + h;
    const float* kv = KV + (size_t)bh * 2048;
    const float* ksm = Ksum + (size_t)bh * 64;
    float acc = 0.f, zden = 0.f;
#pragma unroll 8
    for (int d = 0; d < 32; ++d) {
      float qv = qrow[h * 32 + d];
      float qs = qv * sq, qc = qv * cq;
      acc = fmaf(qs, kv[d * 32 + e], acc);
      acc = fmaf(qc, kv[(32 + d) * 32 + e], acc);
      zden = fmaf(qs, ksm[d], zden);
      zden = fmaf(qc, ksm[32 + d], zden);
    }
    float zc = fminf(fmaxf(zden, 1e-4f), 10.0f);
    attn[(size_t)t * 256 + h * 32 + e] = acc * (1.0f / zc);
  }
}

// out2 [t][256] -> a3p [b][c][40][40]
__global__ __launch_bounds__(256) void transpose_kernel(
    const float* __restrict__ X, float* __restrict__ Y) {
  __shared__ float buf[40 * 257];
  int y = blockIdx.x, b = blockIdx.y;
  int tid = threadIdx.x;
  size_t t0 = (size_t)b * 1600 + y * 40;
  for (int it = 0; it < 40; ++it)
    buf[it * 257 + tid] = X[(t0 + it) * 256 + tid];
  __syncthreads();
  for (int it = 0; it < 40; ++it) {
    int idx = it * 256 + tid;
    int c = idx / 40, x = idx - c * 40;
    Y[((size_t)(b * 256 + c) * 1600) + y * 40 + x] = buf[x * 257 + c];
  }
}

// half-pixel bilinear 40->80 with edge clamp
__device__ __forceinline__ float bilin40(const float* sm, int Y, int X) {
  float fy = Y * 0.5f - 0.25f;
  int iy = (int)floorf(fy);
  float dy = fy - (float)iy;
  int y0 = iy < 0 ? 0 : iy;
  int y1 = (iy + 1) > 39 ? 39 : (iy + 1);
  float fx = X * 0.5f - 0.25f;
  int ix = (int)floorf(fx);
  float dx = fx - (float)ix;
  int x0 = ix < 0 ? 0 : ix;
  int x1 = (ix + 1) > 39 ? 39 : (ix + 1);
  float v00 = sm[y0 * 40 + x0], v01 = sm[y0 * 40 + x1];
  float v10 = sm[y1 * 40 + x0], v11 = sm[y1 * 40 + x1];
  return (1.f - dy) * ((1.f - dx) * v00 + dx * v01) +
         dy * ((1.f - dx) * v10 + dx * v11);
}

__global__ __launch_bounds__(256) void upsample_mul_kernel(
    const float* __restrict__ src, const float* __restrict__ a3, float* __restrict__ out) {
  __shared__ float sm[1600];
  int c = blockIdx.x, b = blockIdx.y;
  size_t sbase = ((size_t)b * 256 + c) * 1600;
  for (int i = threadIdx.x; i < 1600; i += 256) sm[i] = src[sbase + i];
  __syncthreads();
  size_t obase = ((size_t)b * 256 + c) * 6400;
  for (int it = 0; it < 25; ++it) {
    int idx = it * 256 + threadIdx.x;
    int Y = idx / 80, X = idx - Y * 80;
    out[obase + idx] = bilin40(sm, Y, X) * a3[obase + idx];
  }
}

__global__ __launch_bounds__(256) void upsample_kernel(
    const float* __restrict__ src, float* __restrict__ out) {
  __shared__ float sm[1600];
  int c = blockIdx.x, b = blockIdx.y;
  size_t sbase = ((size_t)b * 512 + c) * 1600;
  for (int i = threadIdx.x; i < 1600; i += 256) sm[i] = src[sbase + i];
  __syncthreads();
  size_t obase = ((size_t)b * 512 + c) * 6400;
  for (int it = 0; it < 25; ++it) {
    int idx = it * 256 + threadIdx.x;
    int Y = idx / 80, X = idx - Y * 80;
    out[obase + idx] = bilin40(sm, Y, X);
  }
}

extern "C" void kernel_launch(void* const* d_in, const int* in_sizes, int n_in,
                              void* d_out, int out_size, void* d_ws, size_t ws_size,
                              hipStream_t stream) {
  const float* a3     = (const float*)d_in[0];
  const float* a4     = (const float*)d_in[1];
  const float* conv_w = (const float*)d_in[2];
  const float* conv_b = (const float*)d_in[3];
  const float* bn_g   = (const float*)d_in[4];
  const float* bn_b   = (const float*)d_in[5];
  const float* q_w    = (const float*)d_in[6];
  const float* q_b    = (const float*)d_in[7];
  const float* q_ln_g = (const float*)d_in[8];
  const float* q_ln_b = (const float*)d_in[9];
  const float* k_w    = (const float*)d_in[10];
  const float* k_b    = (const float*)d_in[11];
  const float* k_ln_g = (const float*)d_in[12];
  const float* k_ln_b = (const float*)d_in[13];
  const float* v_w    = (const float*)d_in[14];
  const float* v_b    = (const float*)d_in[15];
  const float* out_w  = (const float*)d_in[16];
  const float* out_b  = (const float*)d_in[17];
  const float* lin1_w = (const float*)d_in[18];
  const float* lin1_b = (const float*)d_in[19];
  const float* lin2_w = (const float*)d_in[20];
  const float* lin2_b = (const float*)d_in[21];
  const float* n1_g   = (const float*)d_in[22];
  const float* n1_b   = (const float*)d_in[23];
  const float* n2_g   = (const float*)d_in[24];
  const float* n2_b   = (const float*)d_in[25];
  (void)in_sizes; (void)n_in; (void)out_size; (void)ws_size;

  float* ws  = (float*)d_ws;
  float* pos = ws + 0;
  float* X3  = ws + 409600;    // slot A
  float* X4  = ws + 6963200;   // slot B
  float* Qb  = ws + 13516800;  // slot C
  float* Kb  = ws + 20070400;  // slot D
  float* Vb  = ws + 26624000;  // slot E
  float* KV  = ws + 33177600;
  float* Ks  = ws + 33439744;
  float* Rb  = ws + 33447936;
  float* a4t = ws + 13516800;  // slots C+D (exactly 13,107,200 floats; dead before Q)
  float* ffh = ws + 13516800;  // overlaps C..R (dead by lin1)
  float* out0 = (float*)d_out;
  float* out1 = out0 + (size_t)16 * 256 * 80 * 80;

  pos_kernel<<<1600, 256, 0, stream>>>(pos);
  avgpool_kernel<<<dim3(40, 16), 256, 0, stream>>>(a3, pos, X3, Rb);
  // a4 [b][k][s] -> a4t [t][k]
  a4t_kernel<<<dim3(25, 8, 16), 256, 0, stream>>>(a4, a4t);
  // conv 1x1 + BN + pos -> X4
  mgemm_kernel<1><<<dim3(200, 2), 256, 0, stream>>>(a4t, conv_w, conv_b, X4, 512, 256, pos, bn_g, bn_b);
  // Q = relu(LN(X3 @ q_w^T + q_b))
  mgemm_kernel<0><<<dim3(200, 2), 256, 0, stream>>>(X3, q_w, q_b, Qb, 256, 256, nullptr, nullptr, nullptr);
  ln_kernel<0><<<6400, 256, 0, stream>>>(Qb, q_ln_g, q_ln_b, nullptr, Qb);
  // K = relu(LN(X4 @ k_w^T + k_b))
  mgemm_kernel<0><<<dim3(200, 2), 256, 0, stream>>>(X4, k_w, k_b, Kb, 256, 256, nullptr, nullptr, nullptr);
  ln_kernel<0><<<6400, 256, 0, stream>>>(Kb, k_ln_g, k_ln_b, nullptr, Kb);
  // V = X4 @ v_w^T + v_b
  mgemm_kernel<0><<<dim3(200, 2), 256, 0, stream>>>(X4, v_w, v_b, Vb, 256, 256, nullptr, nullptr, nullptr);
  // linear attention
  kv_kernel<<<128, 256, 0, stream>>>(Kb, Vb, KV, Ks);
  attn_kernel<<<3200, 256, 0, stream>>>(Qb, KV, Ks, X3 /*attn*/);
  // out-proj -> tmp1 (slot E), then out1 = R + LN1(tmp1) -> X4
  mgemm_kernel<0><<<dim3(200, 2), 256, 0, stream>>>(X3, out_w, out_b, Vb, 256, 256, nullptr, nullptr, nullptr);
  ln_kernel<1><<<6400, 256, 0, stream>>>(Vb, n1_g, n1_b, Rb, X4 /*out1*/);
  // FFN
  mgemm_kernel<2><<<dim3(200, 8), 256, 0, stream>>>(X4, lin1_w, lin1_b, ffh, 256, 1024, nullptr, nullptr, nullptr);
  mgemm_kernel<0><<<dim3(200, 2), 256, 0, stream>>>(ffh, lin2_w, lin2_b, X3 /*tmp2*/, 1024, 256, nullptr, nullptr, nullptr);
  ln_kernel<1><<<6400, 256, 0, stream>>>(X3, n2_g, n2_b, X4 /*res=out1*/, X3 /*out2 in-place*/);
  // out2 [t][c] -> a3p [b][c][40][40], then upsample*a3 ; a4 upsample
  transpose_kernel<<<dim3(40, 16), 256, 0, stream>>>(X3, Qb /*a3p*/);
  upsample_mul_kernel<<<dim3(256, 16), 256, 0, stream>>>(Qb, a3, out0);
  upsample_kernel<<<dim3(512, 16), 256, 0, stream>>>(a4, out1);
}

// Round 3
// 455.176 us; speedup vs baseline: 2.4578x; 1.4874x over previous
//
#include <hip/hip_runtime.h>
#include <math.h>

// ---------------------------------------------------------------------------
// Round 3: bf16 intermediates + LN fused into GEMM epilogues + avgpool rework
// Shapes (idx==10): bs=16, c=256, h=w=40, S=1600, T=25600, heads=8, hd=32
// ws float-offsets:
//   POS 0 | WBF 409600(bf16 weights) | KV 868352 | KS 1130496 | KVP 1138688
//   KSP 2449408 | X3bf 2490368 | X4bf 5767168 | QBbf 9043968 | KBbf 12320768
//   VBbf 15597568 | OUT1bf 18874368 | A4T/FFHbf 22151168 (.. 35258368)
//   OUT2f32 9043968 (reuses QB+KB) | A3Pf32 15597568 (reuses VB+OUT1)
// ---------------------------------------------------------------------------

typedef __attribute__((ext_vector_type(8))) short bf16x8;
typedef __attribute__((ext_vector_type(8))) unsigned short us8;
typedef __attribute__((ext_vector_type(4))) unsigned short us4h;
typedef __attribute__((ext_vector_type(4))) float f32x4;

__device__ __forceinline__ unsigned short f2bf(float f) {
  unsigned int u = __float_as_uint(f);
  u += 0x7fff + ((u >> 16) & 1);  // RNE
  return (unsigned short)(u >> 16);
}
__device__ __forceinline__ float bf2f(unsigned short u) {
  return __uint_as_float(((unsigned int)u) << 16);
}

// --- all weights -> bf16 (917504 elements total) ---
__global__ __launch_bounds__(256) void wprep_kernel(
    const float* __restrict__ cw, const float* __restrict__ qw,
    const float* __restrict__ kw, const float* __restrict__ vw,
    const float* __restrict__ ow, const float* __restrict__ l1w,
    const float* __restrict__ l2w, unsigned short* __restrict__ wbf) {
  int gid = blockIdx.x * 256 + threadIdx.x;  // 114688 threads
  size_t e0 = (size_t)gid * 8;
  const float* src; size_t off;
  if (e0 < 131072)      { src = cw;  off = e0; }
  else if (e0 < 196608) { src = qw;  off = e0 - 131072; }
  else if (e0 < 262144) { src = kw;  off = e0 - 196608; }
  else if (e0 < 327680) { src = vw;  off = e0 - 262144; }
  else if (e0 < 393216) { src = ow;  off = e0 - 327680; }
  else if (e0 < 655360) { src = l1w; off = e0 - 393216; }
  else                  { src = l2w; off = e0 - 655360; }
  float4 v0 = *(const float4*)(src + off);
  float4 v1 = *(const float4*)(src + off + 4);
  us8 r;
  r[0] = f2bf(v0.x); r[1] = f2bf(v0.y); r[2] = f2bf(v0.z); r[3] = f2bf(v0.w);
  r[4] = f2bf(v1.x); r[5] = f2bf(v1.y); r[6] = f2bf(v1.z); r[7] = f2bf(v1.w);
  *(us8*)(wbf + e0) = r;
}

// pos[s][c]
__global__ void pos_kernel(float* __restrict__ pos) {
  int s = blockIdx.x, c = threadIdx.x;
  int y = s / 40, x = s - y * 40;
  int quad = c >> 6, i = c & 63;
  float omega = expf(-(float)i * (9.2103403719761836f / 64.0f));
  float coord = (quad < 2) ? (float)y : (float)x;
  float a = coord * omega;
  pos[s * 256 + c] = (quad & 1) ? cosf(a) : sinf(a);
}

// a3 (b,c,80,80) -> X3bf[t][c] = avgpool2 + pos (bf16) ; block = (y,b), 640 thr
__global__ __launch_bounds__(640) void avgpool_kernel(
    const float* __restrict__ a3, const float* __restrict__ pos,
    unsigned short* __restrict__ X3) {
  __shared__ float buf2[256][44];  // [c][x], stride 44 (16B-aligned float4 rows)
  int y = blockIdx.x, b = blockIdx.y;
  int tid = threadIdx.x;
  int x2 = tid % 20, cq = tid / 20;  // 32 c-groups x 20 x-quads
#pragma unroll
  for (int it = 0; it < 8; ++it) {
    int c = cq + 32 * it;
    const float* p = a3 + (((size_t)(b * 256 + c) * 80 + 2 * y) * 80 + x2 * 4);
    float4 r0 = *(const float4*)p;
    float4 r1 = *(const float4*)(p + 80);
    buf2[c][2 * x2]     = 0.25f * ((r0.x + r0.y) + (r1.x + r1.y));
    buf2[c][2 * x2 + 1] = 0.25f * ((r0.z + r0.w) + (r1.z + r1.w));
  }
  __syncthreads();
  size_t t0 = (size_t)b * 1600 + y * 40;
  int sbase = y * 40;
#pragma unroll
  for (int it = 0; it < 4; ++it) {
    int idx = it * 640 + tid;          // 0..2559
    int c = idx & 255, xq = idx >> 8;  // xq 0..9
    int x0 = xq * 4;
    float4 v = *(const float4*)&buf2[c][x0];
#pragma unroll
    for (int j = 0; j < 4; ++j) {
      float pv = pos[(size_t)(sbase + x0 + j) * 256 + c];
      float vv = (j == 0) ? v.x : (j == 1) ? v.y : (j == 2) ? v.z : v.w;
      X3[(t0 + x0 + j) * 256 + c] = f2bf(vv + pv);
    }
  }
}

// a4 [b][k][s] fp32 -> a4t [b*1600+s][k] bf16
__global__ __launch_bounds__(256) void a4t_kernel(
    const float* __restrict__ a4, unsigned short* __restrict__ a4t) {
  __shared__ float buf[64][65];
  int s0 = blockIdx.x * 64, k0 = blockIdx.y * 64, b = blockIdx.z;
  const float* src = a4 + ((size_t)b * 512 + k0) * 1600 + s0;
#pragma unroll
  for (int p = 0; p < 4; ++p) {
    int idx = p * 256 + threadIdx.x;
    int kk = idx >> 4, s4 = (idx & 15) * 4;
    float4 v = *(const float4*)(src + (size_t)kk * 1600 + s4);
    buf[kk][s4 + 0] = v.x; buf[kk][s4 + 1] = v.y;
    buf[kk][s4 + 2] = v.z; buf[kk][s4 + 3] = v.w;
  }
  __syncthreads();
  unsigned short* dst = a4t + ((size_t)b * 1600 + s0) * 512 + k0;
#pragma unroll
  for (int p = 0; p < 4; ++p) {
    int idx = p * 256 + threadIdx.x;
    int ss = idx >> 4, kq = (idx & 15) * 4;
    us4h v;
    v[0] = f2bf(buf[kq + 0][ss]); v[1] = f2bf(buf[kq + 1][ss]);
    v[2] = f2bf(buf[kq + 2][ss]); v[3] = f2bf(buf[kq + 3][ss]);
    *(us4h*)(dst + (size_t)ss * 512 + kq) = v;
  }
}

// ---------------------------------------------------------------------------
// fgemm: BM=64, BN=256, BK=32; 256 thr = 4 waves, wave-tile 32x128 (2x8 frags)
// A bf16 [M][K], W bf16 [N][K]. EPI: 0 plain->bf16, 1 conv BN+pos->bf16,
// 2 LN+ReLU->bf16, 3 LN + (X3-pos) residual ->bf16, 4 GELU->bf16,
// 5 LN + out1 residual ->fp32
// ---------------------------------------------------------------------------
template<int EPI>
__global__ __launch_bounds__(256) void fgemm(
    const unsigned short* __restrict__ A, const unsigned short* __restrict__ W,
    const float* __restrict__ bias, void* __restrict__ outp,
    const int K, const int ldN,
    const float* __restrict__ posb,
    const float* __restrict__ g1, const float* __restrict__ b1,
    const unsigned short* __restrict__ res) {
  __shared__ __align__(16) unsigned short Albs[64][40];
  __shared__ __align__(16) unsigned short Wlds[256][40];
  __shared__ float part[2][64][2];
  int tid = threadIdx.x;
  int lane = tid & 63, w = tid >> 6;
  int m0 = (w >> 1) * 32, n0 = (w & 1) * 128;
  int g = lane >> 4, cl = lane & 15;
  int t0 = blockIdx.x * 64, o0 = blockIdx.y * 256;
  f32x4 acc[2][8] = {};
  int arr = tid >> 2, acol = (tid & 3) * 8;

  for (int k0 = 0; k0 < K; k0 += 32) {
    __syncthreads();
    *(us8*)&Albs[arr][acol] = *(const us8*)(A + (size_t)(t0 + arr) * K + (k0 + acol));
#pragma unroll
    for (int p = 0; p < 4; ++p) {
      int idx = p * 256 + tid;
      int rr = idx >> 2, cc = (idx & 3) * 8;
      *(us8*)&Wlds[rr][cc] = *(const us8*)(W + (size_t)(o0 + rr) * K + (k0 + cc));
    }
    __syncthreads();
    bf16x8 af[2], bw[8];
#pragma unroll
    for (int ms = 0; ms < 2; ++ms)
      af[ms] = *(const bf16x8*)&Albs[m0 + ms * 16 + cl][g * 8];
#pragma unroll
    for (int ns = 0; ns < 8; ++ns)
      bw[ns] = *(const bf16x8*)&Wlds[n0 + ns * 16 + cl][g * 8];
#pragma unroll
    for (int ms = 0; ms < 2; ++ms)
#pragma unroll
      for (int ns = 0; ns < 8; ++ns)
        acc[ms][ns] = __builtin_amdgcn_mfma_f32_16x16x32_bf16(af[ms], bw[ns], acc[ms][ns], 0, 0, 0);
  }

  float bv[8];
#pragma unroll
  for (int ns = 0; ns < 8; ++ns) bv[ns] = bias[o0 + n0 + ns * 16 + cl];
  int sbase = t0 % 1600;  // 1600 % 64 == 0: block never crosses batch

  if constexpr (EPI == 2 || EPI == 3 || EPI == 5) {
#pragma unroll
    for (int ms = 0; ms < 2; ++ms) {
#pragma unroll
      for (int i = 0; i < 4; ++i) {
        float p = 0.f, q = 0.f;
#pragma unroll
        for (int ns = 0; ns < 8; ++ns) {
          float v = acc[ms][ns][i] + bv[ns];
          p += v; q += v * v;
        }
        p += __shfl_xor(p, 1); q += __shfl_xor(q, 1);
        p += __shfl_xor(p, 2); q += __shfl_xor(q, 2);
        p += __shfl_xor(p, 4); q += __shfl_xor(q, 4);
        p += __shfl_xor(p, 8); q += __shfl_xor(q, 8);
        if (cl == 0) {
          int rl = m0 + ms * 16 + g * 4 + i;
          part[w & 1][rl][0] = p;
          part[w & 1][rl][1] = q;
        }
      }
    }
    __syncthreads();
  }

  unsigned short* ob = (unsigned short*)outp;
  float* of = (float*)outp;
#pragma unroll
  for (int ms = 0; ms < 2; ++ms) {
#pragma unroll
    for (int i = 0; i < 4; ++i) {
      int rl = m0 + ms * 16 + g * 4 + i;
      int t = t0 + rl;
      float mean = 0.f, inv = 0.f;
      if constexpr (EPI == 2 || EPI == 3 || EPI == 5) {
        float sp = part[0][rl][0] + part[1][rl][0];
        float sq = part[0][rl][1] + part[1][rl][1];
        mean = sp * (1.f / 256.f);
        float var = sq * (1.f / 256.f) - mean * mean;
        inv = rsqrtf(var + 1e-5f);
      }
#pragma unroll
      for (int ns = 0; ns < 8; ++ns) {
        int col = n0 + ns * 16 + cl;  // local col; global = o0+col
        float v = acc[ms][ns][i] + bv[ns];
        size_t oidx = (size_t)t * ldN + o0 + col;
        if constexpr (EPI == 0) {
          ob[oidx] = f2bf(v);
        } else if constexpr (EPI == 1) {
          const float is = 0.99999500003749968f;  // 1/sqrt(1+1e-5)
          float y = v * (is * g1[col]) + b1[col] + posb[(size_t)(sbase + rl) * 256 + col];
          ob[oidx] = f2bf(y);
        } else if constexpr (EPI == 2) {
          float y = (v - mean) * inv * g1[col] + b1[col];
          ob[oidx] = f2bf(fmaxf(y, 0.f));
        } else if constexpr (EPI == 3) {
          float y = (v - mean) * inv * g1[col] + b1[col];
          y += bf2f(res[(size_t)t * 256 + col]) - posb[(size_t)(sbase + rl) * 256 + col];
          ob[oidx] = f2bf(y);
        } else if constexpr (EPI == 4) {
          float y = 0.5f * v * (1.f + erff(v * 0.7071067811865475f));
          ob[oidx] = f2bf(y);
        } else {
          float y = (v - mean) * inv * g1[col] + b1[col];
          y += bf2f(res[(size_t)t * 256 + col]);
          of[oidx] = y;
        }
      }
    }
  }
}

// Per (bh, s-split of 320): partial KV[d][e], Ksum[d]
__global__ __launch_bounds__(256) void kv_kernel(
    const unsigned short* __restrict__ Kb, const unsigned short* __restrict__ Vb,
    float* __restrict__ KVp, float* __restrict__ Ksp) {
  __shared__ float Kc[64][32];
  __shared__ float Vc[64][32];
  __shared__ float sv[64], cv[64];
  __shared__ float red[4][64];
  int bx = blockIdx.x;
  int bh = bx / 5, sp = bx - bh * 5;
  int b = bh >> 3, h = bh & 7;
  int tid = threadIdx.x;
  int e = tid & 31, dg = tid >> 5;
  int d4 = dg * 4;
  int dks = tid & 63, partid = tid >> 6;
  float accs[4] = {0.f, 0.f, 0.f, 0.f};
  float accc[4] = {0.f, 0.f, 0.f, 0.f};
  float ks = 0.f;
  size_t base = ((size_t)b * 1600) * 256 + h * 32;
  for (int s0 = sp * 320; s0 < sp * 320 + 320; s0 += 64) {
    __syncthreads();
#pragma unroll
    for (int p = 0; p < 8; ++p) {
      int si = dg + p * 8;
      Kc[si][e] = bf2f(Kb[base + (size_t)(s0 + si) * 256 + e]);
      Vc[si][e] = bf2f(Vb[base + (size_t)(s0 + si) * 256 + e]);
    }
    if (tid < 64) {
      float wv = 1.5707963267948966f * (float)(s0 + tid + 1) * (1.0f / 1600.0f);
      sv[tid] = sinf(wv);
      cv[tid] = cosf(wv);
    }
    __syncthreads();
#pragma unroll 8
    for (int si = 0; si < 64; ++si) {
      float vv = Vc[si][e];
      float sn = sv[si], cs = cv[si];
      float4 k4 = *(const float4*)&Kc[si][d4];
      float p0 = k4.x * vv, p1 = k4.y * vv, p2 = k4.z * vv, p3 = k4.w * vv;
      accs[0] = fmaf(p0, sn, accs[0]); accc[0] = fmaf(p0, cs, accc[0]);
      accs[1] = fmaf(p1, sn, accs[1]); accc[1] = fmaf(p1, cs, accc[1]);
      accs[2] = fmaf(p2, sn, accs[2]); accc[2] = fmaf(p2, cs, accc[2]);
      accs[3] = fmaf(p3, sn, accs[3]); accc[3] = fmaf(p3, cs, accc[3]);
    }
#pragma unroll 4
    for (int q = 0; q < 16; ++q) {
      int si = partid * 16 + q;
      float kvv = (dks < 32) ? Kc[si][dks] * sv[si] : Kc[si][dks - 32] * cv[si];
      ks += kvv;
    }
  }
  red[partid][dks] = ks;
  __syncthreads();
  size_t ob = (size_t)sp * 128 + bh;
  if (tid < 64)
    Ksp[ob * 64 + tid] = (red[0][tid] + red[1][tid]) + (red[2][tid] + red[3][tid]);
#pragma unroll
  for (int i = 0; i < 4; ++i) {
    KVp[ob * 2048 + (d4 + i) * 32 + e] = accs[i];
    KVp[ob * 2048 + (32 + d4 + i) * 32 + e] = accc[i];
  }
}

__global__ __launch_bounds__(256) void kvred_kernel(
    const float* __restrict__ KVp, const float* __restrict__ Ksp,
    float* __restrict__ KV, float* __restrict__ Ks) {
  int bh = blockIdx.x, tid = threadIdx.x;
  size_t o = (size_t)bh * 2048 + tid * 8;
  float4 s0 = make_float4(0, 0, 0, 0), s1 = make_float4(0, 0, 0, 0);
#pragma unroll
  for (int sp = 0; sp < 5; ++sp) {
    const float* p = KVp + ((size_t)sp * 128 + bh) * 2048 + tid * 8;
    float4 a = *(const float4*)p;
    float4 b2 = *(const float4*)(p + 4);
    s0.x += a.x; s0.y += a.y; s0.z += a.z; s0.w += a.w;
    s1.x += b2.x; s1.y += b2.y; s1.z += b2.z; s1.w += b2.w;
  }
  *(float4*)(KV + o) = s0;
  *(float4*)(KV + o + 4) = s1;
  if (tid < 64) {
    float t = 0.f;
#pragma unroll
    for (int sp = 0; sp < 5; ++sp) t += Ksp[((size_t)sp * 128 + bh) * 64 + tid];
    Ks[bh * 64 + tid] = t;
  }
}

// attn[t][h*32+e] bf16
__global__ __launch_bounds__(256) void attn_kernel(
    const unsigned short* __restrict__ Qb, const float* __restrict__ KV,
    const float* __restrict__ Ksum, unsigned short* __restrict__ attn) {
  int grp = threadIdx.x >> 5;
  int e = threadIdx.x & 31;
  int t = blockIdx.x * 8 + grp;
  int b = t / 1600, s = t - b * 1600;
  float wv = 1.5707963267948966f * (float)(s + 1) * (1.0f / 1600.0f);
  float sq = sinf(wv), cq = cosf(wv);
  const unsigned short* qrow = Qb + (size_t)t * 256;
  for (int h = 0; h < 8; ++h) {
    int bh = b * 8 + h;
    const float* kv = KV + (size_t)bh * 2048;
    const float* ksm = Ksum + (size_t)bh * 64;
    float qe = bf2f(qrow[h * 32 + e]);
    float zp = qe * (sq * ksm[e] + cq * ksm[32 + e]);
    zp += __shfl_xor(zp, 1); zp += __shfl_xor(zp, 2);
    zp += __shfl_xor(zp, 4); zp += __shfl_xor(zp, 8); zp += __shfl_xor(zp, 16);
    float acc = 0.f;
#pragma unroll 8
    for (int d = 0; d < 32; ++d) {
      float qv = bf2f(qrow[h * 32 + d]);
      acc = fmaf(qv * sq, kv[d * 32 + e], acc);
      acc = fmaf(qv * cq, kv[(32 + d) * 32 + e], acc);
    }
    float zc = fminf(fmaxf(zp, 1e-4f), 10.0f);
    attn[(size_t)t * 256 + h * 32 + e] = f2bf(acc * (1.0f / zc));
  }
}

// out2 fp32 [t][256] -> a3p fp32 [b][c][40][40]
__global__ __launch_bounds__(256) void transpose_kernel(
    const float* __restrict__ X, float* __restrict__ Y) {
  __shared__ float buf[40 * 257];
  int y = blockIdx.x, b = blockIdx.y;
  int tid = threadIdx.x;
  size_t t0 = (size_t)b * 1600 + y * 40;
  for (int it = 0; it < 40; ++it)
    buf[it * 257 + tid] = X[(t0 + it) * 256 + tid];
  __syncthreads();
  for (int it = 0; it < 40; ++it) {
    int idx = it * 256 + tid;
    int c = idx / 40, x = idx - c * 40;
    Y[((size_t)(b * 256 + c) * 1600) + y * 40 + x] = buf[x * 257 + c];
  }
}

__device__ __forceinline__ float bilin40(const float* sm, int Y, int X) {
  float fy = Y * 0.5f - 0.25f;
  int iy = (int)floorf(fy);
  float dy = fy - (float)iy;
  int y0 = iy < 0 ? 0 : iy;
  int y1 = (iy + 1) > 39 ? 39 : (iy + 1);
  float fx = X * 0.5f - 0.25f;
  int ix = (int)floorf(fx);
  float dx = fx - (float)ix;
  int x0 = ix < 0 ? 0 : ix;
  int x1 = (ix + 1) > 39 ? 39 : (ix + 1);
  float v00 = sm[y0 * 40 + x0], v01 = sm[y0 * 40 + x1];
  float v10 = sm[y1 * 40 + x0], v11 = sm[y1 * 40 + x1];
  return (1.f - dy) * ((1.f - dx) * v00 + dx * v01) +
         dy * ((1.f - dx) * v10 + dx * v11);
}

__global__ __launch_bounds__(256) void upsample_mul_kernel(
    const float* __restrict__ src, const float* __restrict__ a3, float* __restrict__ out) {
  __shared__ float sm[1600];
  int c = blockIdx.x, b = blockIdx.y;
  size_t sbase = ((size_t)b * 256 + c) * 1600;
  for (int i = threadIdx.x; i < 1600; i += 256) sm[i] = src[sbase + i];
  __syncthreads();
  size_t obase = ((size_t)b * 256 + c) * 6400;
  for (int it = 0; it < 25; ++it) {
    int idx = it * 256 + threadIdx.x;
    int Y = idx / 80, X = idx - Y * 80;
    out[obase + idx] = bilin40(sm, Y, X) * a3[obase + idx];
  }
}

__global__ __launch_bounds__(256) void upsample_kernel(
    const float* __restrict__ src, float* __restrict__ out) {
  __shared__ float sm[1600];
  int c = blockIdx.x, b = blockIdx.y;
  size_t sbase = ((size_t)b * 512 + c) * 1600;
  for (int i = threadIdx.x; i < 1600; i += 256) sm[i] = src[sbase + i];
  __syncthreads();
  size_t obase = ((size_t)b * 512 + c) * 6400;
  for (int it = 0; it < 25; ++it) {
    int idx = it * 256 + threadIdx.x;
    int Y = idx / 80, X = idx - Y * 80;
    out[obase + idx] = bilin40(sm, Y, X);
  }
}

extern "C" void kernel_launch(void* const* d_in, const int* in_sizes, int n_in,
                              void* d_out, int out_size, void* d_ws, size_t ws_size,
                              hipStream_t stream) {
  const float* a3     = (const float*)d_in[0];
  const float* a4     = (const float*)d_in[1];
  const float* conv_w = (const float*)d_in[2];
  const float* conv_b = (const float*)d_in[3];
  const float* bn_g   = (const float*)d_in[4];
  const float* bn_b   = (const float*)d_in[5];
  const float* q_w    = (const float*)d_in[6];
  const float* q_b    = (const float*)d_in[7];
  const float* q_ln_g = (const float*)d_in[8];
  const float* q_ln_b = (const float*)d_in[9];
  const float* k_w    = (const float*)d_in[10];
  const float* k_b    = (const float*)d_in[11];
  const float* k_ln_g = (const float*)d_in[12];
  const float* k_ln_b = (const float*)d_in[13];
  const float* v_w    = (const float*)d_in[14];
  const float* v_b    = (const float*)d_in[15];
  const float* out_w  = (const float*)d_in[16];
  const float* out_b  = (const float*)d_in[17];
  const float* lin1_w = (const float*)d_in[18];
  const float* lin1_b = (const float*)d_in[19];
  const float* lin2_w = (const float*)d_in[20];
  const float* lin2_b = (const float*)d_in[21];
  const float* n1_g   = (const float*)d_in[22];
  const float* n1_b   = (const float*)d_in[23];
  const float* n2_g   = (const float*)d_in[24];
  const float* n2_b   = (const float*)d_in[25];
  (void)in_sizes; (void)n_in; (void)out_size; (void)ws_size;

  float* ws = (float*)d_ws;
  float* pos  = ws + 0;
  unsigned short* wbf = (unsigned short*)(ws + 409600);
  float* KV   = ws + 868352;
  float* Ks   = ws + 1130496;
  float* KVp  = ws + 1138688;
  float* Ksp  = ws + 2449408;
  unsigned short* X3b  = (unsigned short*)(ws + 2490368);
  unsigned short* X4b  = (unsigned short*)(ws + 5767168);
  unsigned short* Qbb  = (unsigned short*)(ws + 9043968);
  unsigned short* Kbb  = (unsigned short*)(ws + 12320768);  // -> attn
  unsigned short* Vbb  = (unsigned short*)(ws + 15597568);
  unsigned short* o1b  = (unsigned short*)(ws + 18874368);
  unsigned short* a4tb = (unsigned short*)(ws + 22151168);  // dead after conv
  unsigned short* ffhb = (unsigned short*)(ws + 22151168);
  float* out2 = ws + 9043968;   // reuses QB+KB (dead)
  float* a3p  = ws + 15597568;  // reuses VB+OUT1 (dead)

  const unsigned short* w_conv = wbf;
  const unsigned short* w_q    = wbf + 131072;
  const unsigned short* w_k    = wbf + 196608;
  const unsigned short* w_v    = wbf + 262144;
  const unsigned short* w_o    = wbf + 327680;
  const unsigned short* w_l1   = wbf + 393216;
  const unsigned short* w_l2   = wbf + 655360;

  float* out0 = (float*)d_out;
  float* out1f = out0 + (size_t)16 * 256 * 80 * 80;

  wprep_kernel<<<448, 256, 0, stream>>>(conv_w, q_w, k_w, v_w, out_w, lin1_w, lin2_w, wbf);
  pos_kernel<<<1600, 256, 0, stream>>>(pos);
  avgpool_kernel<<<dim3(40, 16), 640, 0, stream>>>(a3, pos, X3b);
  a4t_kernel<<<dim3(25, 8, 16), 256, 0, stream>>>(a4, a4tb);
  // conv + BN + pos -> X4
  fgemm<1><<<dim3(400, 1), 256, 0, stream>>>(a4tb, w_conv, conv_b, X4b, 512, 256, pos, bn_g, bn_b, nullptr);
  // Q = relu(LN(X3 @ qw + qb))
  fgemm<2><<<dim3(400, 1), 256, 0, stream>>>(X3b, w_q, q_b, Qbb, 256, 256, nullptr, q_ln_g, q_ln_b, nullptr);
  // K = relu(LN(X4 @ kw + kb))
  fgemm<2><<<dim3(400, 1), 256, 0, stream>>>(X4b, w_k, k_b, Kbb, 256, 256, nullptr, k_ln_g, k_ln_b, nullptr);
  // V = X4 @ vw + vb
  fgemm<0><<<dim3(400, 1), 256, 0, stream>>>(X4b, w_v, v_b, Vbb, 256, 256, nullptr, nullptr, nullptr, nullptr);
  // linear attention
  kv_kernel<<<640, 256, 0, stream>>>(Kbb, Vbb, KVp, Ksp);
  kvred_kernel<<<128, 256, 0, stream>>>(KVp, Ksp, KV, Ks);
  attn_kernel<<<3200, 256, 0, stream>>>(Qbb, KV, Ks, Kbb /*attn*/);
  // out1 = (X3-pos) + LN1(attn @ ow + ob)   -> o1b (bf16)
  fgemm<3><<<dim3(400, 1), 256, 0, stream>>>(Kbb, w_o, out_b, o1b, 256, 256, pos, n1_g, n1_b, X3b);
  // ffh = gelu(out1 @ l1w + l1b)
  fgemm<4><<<dim3(400, 4), 256, 0, stream>>>(o1b, w_l1, lin1_b, ffhb, 256, 1024, nullptr, nullptr, nullptr, nullptr);
  // out2 = out1 + LN2(ffh @ l2w + l2b)  (fp32)
  fgemm<5><<<dim3(400, 1), 256, 0, stream>>>(ffhb, w_l2, lin2_b, out2, 1024, 256, nullptr, n2_g, n2_b, o1b);
  // transpose, upsample
  transpose_kernel<<<dim3(40, 16), 256, 0, stream>>>(out2, a3p);
  upsample_mul_kernel<<<dim3(256, 16), 256, 0, stream>>>(a3p, a3, out0);
  upsample_kernel<<<dim3(512, 16), 256, 0, stream>>>(a4, out1f);
}